// Round 26
// baseline (57.202 us; speedup 1.0000x reference)
//
#include <hip/hip_runtime.h>
#include <hip/hip_bf16.h>
#include <cstdint>
#include <cstddef>

typedef __bf16 bf16_t;
typedef bf16_t bf16x8 __attribute__((ext_vector_type(8)));
typedef float f32x4 __attribute__((ext_vector_type(4)));
typedef float f32x16 __attribute__((ext_vector_type(16)));
typedef unsigned short u16;
typedef u16 u16x8 __attribute__((ext_vector_type(8)));

#define S_LEN 2048
#define NB 2
#define NH 8
#define DHD 64
#define DM 512

static __device__ __forceinline__ u16 bfbits(float f) {
  union { __bf16 h; u16 u; } c; c.h = (__bf16)f; return c.u;
}
static __device__ __forceinline__ float bits2f(u16 b) {
  union { u16 u; __bf16 h; } c; c.u = b; return (float)c.h;
}
static __device__ __forceinline__ uint32_t pkbf(float a, float b) {
  union { __bf16 h[2]; uint32_t u; } c;
  c.h[0] = (__bf16)a; c.h[1] = (__bf16)b;
  return c.u;
}
// async global->LDS, 16B per lane; LDS dest is wave-uniform base + lane*16
static __device__ __forceinline__ void gload16(const void* g, void* l) {
  __builtin_amdgcn_global_load_lds(
      (const __attribute__((address_space(1))) uint32_t*)g,
      (__attribute__((address_space(3))) uint32_t*)l, 16, 0, 0);
}

// slots for split-K partials: per bh, qb 5..15, 4 waves, nc chunks
static __device__ __forceinline__ int slot_of(int bh, int t32, int chunk) {
  int qb = t32 >> 2;
  int nc = (2 * (qb + 1) + 9) / 10;
  int off;
  if (qb < 10) off = (qb - 5) * 8;
  else if (qb < 15) off = 40 + (qb - 10) * 12;
  else off = 100;
  return bh * 116 + off + (t32 & 3) * nc + chunk;
}

// ---------------------------------------------------------------------------
// Projection GEMM: P = relu(X @ W^T + b); Q pre-scaled 0.125*log2e.
// 128x128 tile, BK=32, 16 steps. FOUR 32 KB fp32 LDS buffers (128 KB total,
// 1 block/CU), 2 k-steps per barrier, stages issued one iteration ahead ->
// youngest stage ~2 compute-steps (~1300cy) old at drain (R22 mechanism).
// 8 barriers. fp32 via global_load_lds (XOR-pre-swizzled source, linear LDS,
// XOR read); cvt at fragment build. Grid 384 = 8 xcd * 12 m * 4 n.
// ---------------------------------------------------------------------------
__launch_bounds__(256, 1)
__global__ void proj_kernel(const float* __restrict__ Xq, const float* __restrict__ Xk,
                            const float* __restrict__ Xv, const float* __restrict__ W,
                            const float* __restrict__ bias,
                            u16* __restrict__ Qw, u16* __restrict__ Kw,
                            u16* __restrict__ Vt64) {
  __shared__ __align__(16) float BUF[4][8192];   // per buf: A 128x32 @0, B 128x32 @4096
  const int bid = blockIdx.x;
  const int xcd = bid & 7;
  const int u = bid >> 3;               // 0..47
  const int n0 = (u & 3) * 128;
  const int mIdx = u >> 2;              // 0..11
  const int mg = (xcd * 12 + mIdx) * 128;
  const int z = mg >> 12;               // 0..2
  const int m_in = mg & 4095;
  const int b = m_in >> 11;
  const int s0m = m_in & (S_LEN - 1);
  const int h0 = n0 >> 6;               // first of 2 heads in this n-span
  const float* __restrict__ X = (z == 0) ? Xq : ((z == 1) ? Xk : Xv);
  X += (size_t)m_in * DM;

  const int t = threadIdx.x;
  const int lane = t & 63;
  const int wid = t >> 6;
  const int wr = wid >> 1, wc = wid & 1;
  const int fr = lane & 15, fg = lane >> 4;

  f32x4 acc[4][4] = {};

  const int lrow = lane >> 3;           // 0..7 within chunk
  const int lblk = lane & 7;            // 16B block within 128B row

  auto stage = [&](int bf, int k0) {
    #pragma unroll
    for (int i = 0; i < 4; ++i) {       // A: 16 chunks of 1KB (8 rows), 4/wave
      int c = wid * 4 + i;
      int r = c * 8 + lrow;
      gload16(X + (size_t)r * DM + k0 + ((lblk ^ (r & 7)) << 2), &BUF[bf][c * 256]);
    }
    #pragma unroll
    for (int i = 0; i < 4; ++i) {       // B: 16 chunks, 4/wave
      int c = wid * 4 + i;
      int r = c * 8 + lrow;
      gload16(W + (size_t)(n0 + r) * DM + k0 + ((lblk ^ (r & 7)) << 2),
              &BUF[bf][4096 + c * 256]);
    }
  };

  // one BK=32 k-step from buffer `buf`
  auto do_step = [&](int buf) {
    const float* Ac = BUF[buf];
    bf16x8 af[4], bfr[4];
    #pragma unroll
    for (int m2 = 0; m2 < 4; ++m2) {
      int r = wr*64 + m2*16 + fr;
      f32x4 lo = *(const f32x4*)&Ac[r*32 + (((2*fg)     ^ (r & 7)) << 2)];
      f32x4 hi = *(const f32x4*)&Ac[r*32 + (((2*fg + 1) ^ (r & 7)) << 2)];
      union { u16x8 s; bf16x8 v; } f;
      f.s[0]=bfbits(lo[0]); f.s[1]=bfbits(lo[1]); f.s[2]=bfbits(lo[2]); f.s[3]=bfbits(lo[3]);
      f.s[4]=bfbits(hi[0]); f.s[5]=bfbits(hi[1]); f.s[6]=bfbits(hi[2]); f.s[7]=bfbits(hi[3]);
      af[m2] = f.v;
    }
    #pragma unroll
    for (int ni = 0; ni < 4; ++ni) {
      int r = wc*64 + ni*16 + fr;
      f32x4 lo = *(const f32x4*)&Ac[4096 + r*32 + (((2*fg)     ^ (r & 7)) << 2)];
      f32x4 hi = *(const f32x4*)&Ac[4096 + r*32 + (((2*fg + 1) ^ (r & 7)) << 2)];
      union { u16x8 s; bf16x8 v; } f;
      f.s[0]=bfbits(lo[0]); f.s[1]=bfbits(lo[1]); f.s[2]=bfbits(lo[2]); f.s[3]=bfbits(lo[3]);
      f.s[4]=bfbits(hi[0]); f.s[5]=bfbits(hi[1]); f.s[6]=bfbits(hi[2]); f.s[7]=bfbits(hi[3]);
      bfr[ni] = f.v;
    }
    __builtin_amdgcn_s_setprio(1);
    #pragma unroll
    for (int m2 = 0; m2 < 4; ++m2)
      #pragma unroll
      for (int ni = 0; ni < 4; ++ni)
        acc[m2][ni] = __builtin_amdgcn_mfma_f32_16x16x32_bf16(af[m2], bfr[ni], acc[m2][ni], 0, 0, 0);
    __builtin_amdgcn_s_setprio(0);
  };

  // 2 steps per barrier; stages issued one full iteration ahead (8 barriers)
  stage(0, 0);
  stage(1, 32);
  int ib = 0;
  for (int i = 0; i < 16; i += 2) {
    __syncthreads();                    // drains stages issued LAST iteration
    if (i + 2 < 16) {
      stage((ib + 2) & 3, (i + 2) * 32);
      stage((ib + 3) & 3, (i + 3) * 32);
    }
    do_step(ib);
    do_step((ib + 1) & 3);
    ib = (ib + 2) & 3;
  }
  __syncthreads();

  const float QSCALE = 0.125f * 1.44269504089f;
  u16* epi = (u16*)&BUF[0][0];          // 128 x 136 u16 = 34 KB, fits pool

  if (z == 2) {
    // stage C^T[e][m] (stride 136); coalesced rows -> Vt64[bh][s/64][d][s%64]
    #pragma unroll
    for (int m2 = 0; m2 < 4; ++m2) {
      #pragma unroll
      for (int ni = 0; ni < 4; ++ni) {
        int e = wc*64 + ni*16 + fr;
        int m = wr*64 + m2*16 + fg*4;
        float bv = bias[n0 + e];
        float v0 = fmaxf(acc[m2][ni][0] + bv, 0.f);
        float v1 = fmaxf(acc[m2][ni][1] + bv, 0.f);
        float v2 = fmaxf(acc[m2][ni][2] + bv, 0.f);
        float v3 = fmaxf(acc[m2][ni][3] + bv, 0.f);
        uint2 w; w.x = pkbf(v0, v1); w.y = pkbf(v2, v3);
        *(uint2*)&epi[e*136 + m] = w;
      }
    }
    __syncthreads();
    const int e2 = t >> 1, mc = (t & 1) * 64;   // e2 0..127, mc 0/64
    const int h = h0 + (e2 >> 6), d = e2 & 63;
    const int sb = (s0m >> 6) + (mc >> 6);
    u16* dst = Vt64 + (((size_t)(b * NH + h) * 32 + sb) * 64 + d) * 64;
    #pragma unroll
    for (int i = 0; i < 8; ++i)
      *(uint4*)(dst + i*8) = *(const uint4*)&epi[e2*136 + mc + i*8];
  } else {
    // stage C[m][e] (stride 136); coalesced rows -> Qw/Kw[bh][s][dh]
    #pragma unroll
    for (int m2 = 0; m2 < 4; ++m2) {
      #pragma unroll
      for (int ni = 0; ni < 4; ++ni) {
        int e = wc*64 + ni*16 + fr;
        float bv = bias[n0 + e];
        #pragma unroll
        for (int r = 0; r < 4; ++r) {
          float v = acc[m2][ni][r] + bv;
          if (z == 0) v *= QSCALE;
          v = fmaxf(v, 0.f);
          epi[(wr*64 + m2*16 + fg*4 + r)*136 + e] = bfbits(v);
        }
      }
    }
    __syncthreads();
    const int mrow = t >> 1, hf = t & 1;
    u16* dst = ((z == 0) ? Qw : Kw) +
               (((size_t)(b * NH + h0 + hf)) * S_LEN + s0m + mrow) * DHD;
    #pragma unroll
    for (int i = 0; i < 8; ++i)
      *(uint4*)(dst + i*8) = *(const uint4*)&epi[mrow*136 + hf*64 + i*8];
  }
}

// longest-first block table: (qb, chunk) for the 34 blocks per bh
static __device__ const uint8_t QBT[34] = {4,5,6,7,8,9,9,10,10,11,11,12,12,13,13,14,14,14,15,15,15,
                                           3,8,13, 2,7,12, 1,6,11, 0,5,10,15};
static __device__ const uint8_t CKT[34] = {0,0,0,0,0,0,1,0,1,0,1,0,1,0,1,0,1,2,0,1,2,
                                           0,1,2, 0,1,2, 0,1,2, 0,1,2,3};

// ---------------------------------------------------------------------------
// Flash attention (R25 verbatim): 4 waves/block, FOUR 64-row K/V LDS buffers,
// 2 steps per barrier, stages one iteration ahead; bulk-bulk step pair fused
// with [PV(s) || QK(s+1)] interleave. Unnormalized p=exp2(s).
// ---------------------------------------------------------------------------
__launch_bounds__(256, 2)
__global__ void attn_kernel(const u16* __restrict__ Qw, const u16* __restrict__ Kw,
                            const u16* __restrict__ Vt64, u16* __restrict__ Opart,
                            float* __restrict__ lbuf, float* __restrict__ out) {
  __shared__ u16 KLDS[4][4096];
  __shared__ u16 VLDS[4][4096];
  const int t = threadIdx.x;
  const int lane = t & 63;
  const int wid = t >> 6;
  const int lam = lane & 31;
  const int hi = lane >> 5;
  const int h8 = hi << 3, h4 = hi << 2;
  const int bid = blockIdx.x;
  const int bh = bid & 15;              // xcd = bid&7
  const int u = bid >> 4;               // 0..33
  const int qb = QBT[u], chunk = CKT[u];
  const int steps_total = (qb + 1) * 2;
  const int sc0 = chunk * 10;
  const int sc1e = sc0 + 10;
  const int sc1 = (sc1e < steps_total) ? sc1e : steps_total;
  const int t32 = qb * 4 + wid;
  const int q0 = qb * 128 + wid * 32;

  const u16* __restrict__ Qh = Qw + (size_t)bh * S_LEN * DHD;
  const u16* __restrict__ Kh = Kw + (size_t)bh * S_LEN * DHD;
  const u16* __restrict__ V64 = Vt64 + (size_t)bh * 32 * 64 * 64;

  bf16x8 qf[4];
  #pragma unroll
  for (int c = 0; c < 4; ++c)
    qf[c] = *(const bf16x8*)(Qh + (size_t)(q0 + lam) * DHD + c*16 + h8);

  const int lrow = lane >> 3;           // 0..7 within chunk
  const int lblk = lane & 7;
  auto stage = [&](int bf, int s) {
    #pragma unroll
    for (int i = 0; i < 2; ++i) {       // K,V: 8 chunks of 1KB each, 2 per wave
      int c = wid * 2 + i;
      int r = c * 8 + lrow;             // 0..63
      int sw = (lblk ^ (r & 7)) << 3;   // XOR-pre-swizzled source block (u16)
      gload16(Kh + (size_t)(s * 64 + r) * 64 + sw, &KLDS[bf][c * 512]);
      gload16(V64 + ((size_t)s * 64 + r) * 64 + sw, &VLDS[bf][c * 512]);
    }
  };

  f32x16 o0 = {}, o1 = {};
  float lsum = 0.f;

  auto softpack = [&](const f32x16& sc, bool msk, bf16x8& pb0v, bf16x8& pb1v) {
    float p[16];
    #pragma unroll
    for (int r = 0; r < 16; ++r) {
      float ev = __builtin_amdgcn_exp2f(sc[r]);
      int kc = (r & 3) + ((r >> 2) << 3) + h4;
      if (msk && kc > lam) ev = 0.f;
      p[r] = ev;
      lsum += ev;
    }
    uint32_t X0 = pkbf(p[0], p[1]),  X1 = pkbf(p[2], p[3]);
    uint32_t X2 = pkbf(p[4], p[5]),  X3 = pkbf(p[6], p[7]);
    uint32_t X4 = pkbf(p[8], p[9]),  X5 = pkbf(p[10], p[11]);
    uint32_t X6 = pkbf(p[12], p[13]), X7 = pkbf(p[14], p[15]);
    asm("v_permlane32_swap_b32 %0, %1" : "+v"(X0), "+v"(X2));
    asm("v_permlane32_swap_b32 %0, %1" : "+v"(X1), "+v"(X3));
    asm("v_permlane32_swap_b32 %0, %1" : "+v"(X4), "+v"(X6));
    asm("v_permlane32_swap_b32 %0, %1" : "+v"(X5), "+v"(X7));
    union U8 { uint32_t u[4]; bf16x8 v; };
    U8 a, bU;
    a.u[0] = X0; a.u[1] = X1; a.u[2] = X2; a.u[3] = X3;
    bU.u[0] = X4; bU.u[1] = X5; bU.u[2] = X6; bU.u[3] = X7;
    pb0v = a.v; pb1v = bU.v;
  };

  auto loadK = [&](int buf, int half, bf16x8* k4) {
    #pragma unroll
    for (int c = 0; c < 4; ++c) {
      int r = half * 32 + lam, e = ((2*c + hi) ^ (r & 7)) * 8;
      k4[c] = *(const bf16x8*)&KLDS[buf][r*64 + e];
    }
  };
  auto loadV = [&](int buf, int off, bf16x8* v0, bf16x8* v1) {
    #pragma unroll
    for (int c2 = 0; c2 < 2; ++c2) {
      int r0 = lam,      e0 = ((off + 2*c2 + hi) ^ (r0 & 7)) * 8;
      int r1 = 32 + lam, e1 = ((off + 2*c2 + hi) ^ (r1 & 7)) * 8;
      v0[c2] = *(const bf16x8*)&VLDS[buf][r0*64 + e0];
      v1[c2] = *(const bf16x8*)&VLDS[buf][r1*64 + e1];
    }
  };

  // R24 single-step path (edge cases)
  auto do_step = [&](int s, int buf) {
    const int d2 = t32 - 2 * s;
    if (d2 < 0) return;
    if (d2 >= 1) {
      bf16x8 kA[4], kB[4];
      loadK(buf, 0, kA);
      loadK(buf, 1, kB);
      f32x16 sA = {}, sB = {};
      __builtin_amdgcn_s_setprio(1);
      #pragma unroll
      for (int c = 0; c < 4; ++c) {
        sA = __builtin_amdgcn_mfma_f32_32x32x16_bf16(kA[c], qf[c], sA, 0, 0, 0);
        sB = __builtin_amdgcn_mfma_f32_32x32x16_bf16(kB[c], qf[c], sB, 0, 0, 0);
      }
      __builtin_amdgcn_s_setprio(0);
      bf16x8 a0, a1, b0v, b1v;
      softpack(sA, false, a0, a1);
      softpack(sB, d2 == 1, b0v, b1v);
      bf16x8 vA0[2], vA1[2], vB0[2], vB1[2];
      loadV(buf, 0, vA0, vA1);
      loadV(buf, 4, vB0, vB1);
      __builtin_amdgcn_s_setprio(1);
      o0 = __builtin_amdgcn_mfma_f32_32x32x16_bf16(vA0[0], a0, o0, 0, 0, 0);
      o1 = __builtin_amdgcn_mfma_f32_32x32x16_bf16(vA1[0], a0, o1, 0, 0, 0);
      o0 = __builtin_amdgcn_mfma_f32_32x32x16_bf16(vA0[1], a1, o0, 0, 0, 0);
      o1 = __builtin_amdgcn_mfma_f32_32x32x16_bf16(vA1[1], a1, o1, 0, 0, 0);
      o0 = __builtin_amdgcn_mfma_f32_32x32x16_bf16(vB0[0], b0v, o0, 0, 0, 0);
      o1 = __builtin_amdgcn_mfma_f32_32x32x16_bf16(vB1[0], b0v, o1, 0, 0, 0);
      o0 = __builtin_amdgcn_mfma_f32_32x32x16_bf16(vB0[1], b1v, o0, 0, 0, 0);
      o1 = __builtin_amdgcn_mfma_f32_32x32x16_bf16(vB1[1], b1v, o1, 0, 0, 0);
      __builtin_amdgcn_s_setprio(0);
    } else {
      bf16x8 kA[4];
      loadK(buf, 0, kA);
      f32x16 sA = {};
      __builtin_amdgcn_s_setprio(1);
      #pragma unroll
      for (int c = 0; c < 4; ++c)
        sA = __builtin_amdgcn_mfma_f32_32x32x16_bf16(kA[c], qf[c], sA, 0, 0, 0);
      __builtin_amdgcn_s_setprio(0);
      bf16x8 a0, a1;
      softpack(sA, true, a0, a1);
      bf16x8 v0[2], v1[2];
      loadV(buf, 0, v0, v1);
      __builtin_amdgcn_s_setprio(1);
      o0 = __builtin_amdgcn_mfma_f32_32x32x16_bf16(v0[0], a0, o0, 0, 0, 0);
      o1 = __builtin_amdgcn_mfma_f32_32x32x16_bf16(v1[0], a0, o1, 0, 0, 0);
      o0 = __builtin_amdgcn_mfma_f32_32x32x16_bf16(v0[1], a1, o0, 0, 0, 0);
      o1 = __builtin_amdgcn_mfma_f32_32x32x16_bf16(v1[1], a1, o1, 0, 0, 0);
      __builtin_amdgcn_s_setprio(0);
    }
  };

  // fused step pair: step s (buf b0i, unmasked) + step s+1 (buf b1i, maskB1)
  auto fused_pair = [&](int b0i, int b1i, bool maskB1) {
    bf16x8 kA0[4], kB0[4];
    loadK(b0i, 0, kA0);
    loadK(b0i, 1, kB0);
    f32x16 sA0 = {}, sB0 = {};
    __builtin_amdgcn_s_setprio(1);
    #pragma unroll
    for (int c = 0; c < 4; ++c) {
      sA0 = __builtin_amdgcn_mfma_f32_32x32x16_bf16(kA0[c], qf[c], sA0, 0, 0, 0);
      sB0 = __builtin_amdgcn_mfma_f32_32x32x16_bf16(kB0[c], qf[c], sB0, 0, 0, 0);
    }
    __builtin_amdgcn_s_setprio(0);
    bf16x8 a00, a01, b00, b01;
    softpack(sA0, false, a00, a01);
    softpack(sB0, false, b00, b01);
    bf16x8 kA1[4], kB1[4];
    loadK(b1i, 0, kA1);
    loadK(b1i, 1, kB1);
    bf16x8 vA0[2], vA1[2], vB0[2], vB1[2];
    loadV(b0i, 0, vA0, vA1);
    loadV(b0i, 4, vB0, vB1);
    f32x16 sA1 = {}, sB1 = {};
    __builtin_amdgcn_s_setprio(1);
    o0  = __builtin_amdgcn_mfma_f32_32x32x16_bf16(vA0[0], a00, o0, 0, 0, 0);
    sA1 = __builtin_amdgcn_mfma_f32_32x32x16_bf16(kA1[0], qf[0], sA1, 0, 0, 0);
    o1  = __builtin_amdgcn_mfma_f32_32x32x16_bf16(vA1[0], a00, o1, 0, 0, 0);
    sB1 = __builtin_amdgcn_mfma_f32_32x32x16_bf16(kB1[0], qf[0], sB1, 0, 0, 0);
    o0  = __builtin_amdgcn_mfma_f32_32x32x16_bf16(vA0[1], a01, o0, 0, 0, 0);
    sA1 = __builtin_amdgcn_mfma_f32_32x32x16_bf16(kA1[1], qf[1], sA1, 0, 0, 0);
    o1  = __builtin_amdgcn_mfma_f32_32x32x16_bf16(vA1[1], a01, o1, 0, 0, 0);
    sB1 = __builtin_amdgcn_mfma_f32_32x32x16_bf16(kB1[1], qf[1], sB1, 0, 0, 0);
    o0  = __builtin_amdgcn_mfma_f32_32x32x16_bf16(vB0[0], b00, o0, 0, 0, 0);
    sA1 = __builtin_amdgcn_mfma_f32_32x32x16_bf16(kA1[2], qf[2], sA1, 0, 0, 0);
    o1  = __builtin_amdgcn_mfma_f32_32x32x16_bf16(vB1[0], b00, o1, 0, 0, 0);
    sB1 = __builtin_amdgcn_mfma_f32_32x32x16_bf16(kB1[2], qf[2], sB1, 0, 0, 0);
    o0  = __builtin_amdgcn_mfma_f32_32x32x16_bf16(vB0[1], b01, o0, 0, 0, 0);
    sA1 = __builtin_amdgcn_mfma_f32_32x32x16_bf16(kA1[3], qf[3], sA1, 0, 0, 0);
    o1  = __builtin_amdgcn_mfma_f32_32x32x16_bf16(vB1[1], b01, o1, 0, 0, 0);
    sB1 = __builtin_amdgcn_mfma_f32_32x32x16_bf16(kB1[3], qf[3], sB1, 0, 0, 0);
    __builtin_amdgcn_s_setprio(0);
    bf16x8 a10, a11, b10, b11;
    softpack(sA1, false, a10, a11);
    softpack(sB1, maskB1, b10, b11);
    bf16x8 wA0[2], wA1[2], wB0[2], wB1[2];
    loadV(b1i, 0, wA0, wA1);
    loadV(b1i, 4, wB0, wB1);
    __builtin_amdgcn_s_setprio(1);
    o0 = __builtin_amdgcn_mfma_f32_32x32x16_bf16(wA0[0], a10, o0, 0, 0, 0);
    o1 = __builtin_amdgcn_mfma_f32_32x32x16_bf16(wA1[0], a10, o1, 0, 0, 0);
    o0 = __builtin_amdgcn_mfma_f32_32x32x16_bf16(wA0[1], a11, o0, 0, 0, 0);
    o1 = __builtin_amdgcn_mfma_f32_32x32x16_bf16(wA1[1], a11, o1, 0, 0, 0);
    o0 = __builtin_amdgcn_mfma_f32_32x32x16_bf16(wB0[0], b10, o0, 0, 0, 0);
    o1 = __builtin_amdgcn_mfma_f32_32x32x16_bf16(wB1[0], b10, o1, 0, 0, 0);
    o0 = __builtin_amdgcn_mfma_f32_32x32x16_bf16(wB0[1], b11, o0, 0, 0, 0);
    o1 = __builtin_amdgcn_mfma_f32_32x32x16_bf16(wB1[1], b11, o1, 0, 0, 0);
    __builtin_amdgcn_s_setprio(0);
  };

  // 2 steps per barrier; stages issued one full iteration ahead.
  stage(0, sc0);
  stage(1, sc0 + 1);
  int ib = 0;
  for (int s = sc0; s < sc1; s += 2) {
    __syncthreads();                    // drains stages issued LAST iteration
    if (s + 2 < sc1) {
      stage((ib + 2) & 3, s + 2);
      stage((ib + 3) & 3, s + 3);
    }
    const int d2s = t32 - 2 * s;        // wave-uniform
    if (d2s >= 3) {
      fused_pair(ib, (ib + 1) & 3, d2s == 3);
    } else {
      do_step(s, ib);
      do_step(s + 1, (ib + 1) & 3);
    }
    ib = (ib + 2) & 3;
  }

  float l = lsum + __shfl_xor(lsum, 32);

  if (qb <= 4) {
    const int b = bh >> 3, hh = bh & 7;
    const float inv = 1.0f / l;
    float* orow = out + (((size_t)(hh * NB + b)) * S_LEN + (q0 + lam)) * DHD;
    #pragma unroll
    for (int r = 0; r < 16; ++r) {
      int d = (r & 3) + ((r >> 2) << 3) + h4;
      orow[d] = o0[r] * inv;
      orow[d + 32] = o1[r] * inv;
    }
  } else {
    const int slot = slot_of(bh, t32, chunk);
    uint32_t w[16] __attribute__((aligned(16)));
    #pragma unroll
    for (int m = 0; m < 8; ++m) {
      w[m]     = pkbf(o0[2*m], o0[2*m+1]);
      w[8 + m] = pkbf(o1[2*m], o1[2*m+1]);
    }
    u16* op = Opart + (size_t)slot * 2048 + (size_t)lane * 32;
    #pragma unroll
    for (int i = 0; i < 4; ++i)
      *(uint4*)(op + i*8) = *(const uint4*)&w[i*4];
    if (lane < 32) lbuf[slot * 32 + lane] = l;
  }
}

// ---------------------------------------------------------------------------
// Combine split-K partials for tiles with qb>=5 (t32 20..63): plain sums.
// ---------------------------------------------------------------------------
__launch_bounds__(256)
__global__ void reduce_kernel(const u16* __restrict__ Opart,
                              const float* __restrict__ lbuf,
                              float* __restrict__ out) {
  const int t = threadIdx.x;
  const int unit = blockIdx.x * 4 + (t >> 6);   // 0..703
  const int bh = unit & 15;
  const int ti = 20 + (unit >> 4);              // t32 20..63
  const int qb = ti >> 2;
  const int nc = (2 * (qb + 1) + 9) / 10;       // 2..4
  const int lane = t & 63;
  const int lam = lane & 31;
  const int h4 = (lane >> 5) << 2;
  const int slot0 = slot_of(bh, ti, 0);

  float O[32];
  #pragma unroll
  for (int i = 0; i < 32; ++i) O[i] = 0.f;
  float L = 0.f;

  for (int c = 0; c < nc; ++c) {
    const u16* op = Opart + (size_t)(slot0 + c) * 2048 + (size_t)lane * 32;
    L += lbuf[(slot0 + c) * 32 + lam];
    #pragma unroll
    for (int i = 0; i < 4; ++i) {
      uint4 v = *(const uint4*)(op + i*8);
      uint32_t a[4] = {v.x, v.y, v.z, v.w};
      #pragma unroll
      for (int jj = 0; jj < 4; ++jj) {
        O[i*8 + 2*jj]     += bits2f((u16)(a[jj] & 0xFFFFu));
        O[i*8 + 2*jj + 1] += bits2f((u16)(a[jj] >> 16));
      }
    }
  }

  const int b = bh >> 3, hh = bh & 7;
  const float inv = 1.0f / L;
  float* orow = out + (((size_t)(hh * NB + b)) * S_LEN + (ti*32 + lam)) * DHD;
  #pragma unroll
  for (int r = 0; r < 16; ++r) {
    int d = (r & 3) + ((r >> 2) << 3) + h4;
    orow[d] = O[r] * inv;
    orow[d + 32] = O[16 + r] * inv;
  }
}

extern "C" void kernel_launch(void* const* d_in, const int* in_sizes, int n_in,
                              void* d_out, int out_size, void* d_ws, size_t ws_size,
                              hipStream_t stream) {
  const float* q = (const float*)d_in[0];
  const float* k = (const float*)d_in[1];
  const float* v = (const float*)d_in[2];
  const float* W = (const float*)d_in[3];
  const float* b = (const float*)d_in[4];

  const size_t elems = (size_t)NB * NH * S_LEN * DHD;  // 2,097,152
  u16* Qw = (u16*)d_ws;
  u16* Kw = Qw + elems;
  u16* Vt64 = Kw + elems;
  u16* Opart = Vt64 + elems;                           // 1856 slots * 4 KiB = 7.25 MiB
  float* lbuf = (float*)(Opart + (size_t)1856 * 2048); // 232 KiB

  proj_kernel<<<dim3(384), dim3(256), 0, stream>>>(q, k, v, W, b, Qw, Kw, Vt64);

  attn_kernel<<<dim3(544), dim3(256), 0, stream>>>(Qw, Kw, Vt64, Opart, lbuf, (float*)d_out);

  reduce_kernel<<<dim3(176), dim3(256), 0, stream>>>(Opart, lbuf, (float*)d_out);
}

// Round 27
// 47.416 us; speedup vs baseline: 1.2064x; 1.2064x over previous
//
#include <hip/hip_runtime.h>
#include <hip/hip_bf16.h>
#include <cstdint>
#include <cstddef>

typedef __bf16 bf16_t;
typedef bf16_t bf16x8 __attribute__((ext_vector_type(8)));
typedef float f32x4 __attribute__((ext_vector_type(4)));
typedef float f32x16 __attribute__((ext_vector_type(16)));
typedef unsigned short u16;
typedef u16 u16x8 __attribute__((ext_vector_type(8)));

#define S_LEN 2048
#define NB 2
#define NH 8
#define DHD 64
#define DM 512

static __device__ __forceinline__ u16 bfbits(float f) {
  union { __bf16 h; u16 u; } c; c.h = (__bf16)f; return c.u;
}
static __device__ __forceinline__ float bits2f(u16 b) {
  union { u16 u; __bf16 h; } c; c.u = b; return (float)c.h;
}
static __device__ __forceinline__ uint32_t pkbf(float a, float b) {
  union { __bf16 h[2]; uint32_t u; } c;
  c.h[0] = (__bf16)a; c.h[1] = (__bf16)b;
  return c.u;
}
// async global->LDS, 16B per lane; LDS dest is wave-uniform base + lane*16
static __device__ __forceinline__ void gload16(const void* g, void* l) {
  __builtin_amdgcn_global_load_lds(
      (const __attribute__((address_space(1))) uint32_t*)g,
      (__attribute__((address_space(3))) uint32_t*)l, 16, 0, 0);
}

// slots for split-K partials: per bh, qb 5..15, 4 waves, nc chunks
static __device__ __forceinline__ int slot_of(int bh, int t32, int chunk) {
  int qb = t32 >> 2;
  int nc = (2 * (qb + 1) + 9) / 10;
  int off;
  if (qb < 10) off = (qb - 5) * 8;
  else if (qb < 15) off = 40 + (qb - 10) * 12;
  else off = 100;
  return bh * 116 + off + (t32 & 3) * nc + chunk;
}

// ---------------------------------------------------------------------------
// Projection GEMM (R13 form): P = relu(X @ W^T + b); Q scaled 0.125*log2e.
// 128x128 tile, BK=32, 16 steps, 2 LDS bufs; fp32 staged via global_load_lds
// (XOR-pre-swizzled source, linear LDS, XOR read); cvt at fragment build.
// ---------------------------------------------------------------------------
__launch_bounds__(256, 2)
__global__ void proj_kernel(const float* __restrict__ Xq, const float* __restrict__ Xk,
                            const float* __restrict__ Xv, const float* __restrict__ W,
                            const float* __restrict__ bias,
                            u16* __restrict__ Qw, u16* __restrict__ Kw,
                            u16* __restrict__ Vt64) {
  __shared__ __align__(16) float BUF[2][8192];   // per buf: A 128x32 @0, B 128x32 @4096
  const int bid = blockIdx.x;
  const int xcd = bid & 7;
  const int u = bid >> 3;               // 0..47
  const int n0 = (u & 3) * 128;
  const int mIdx = u >> 2;              // 0..11
  const int mg = (xcd * 12 + mIdx) * 128;
  const int z = mg >> 12;               // 0..2
  const int m_in = mg & 4095;
  const int b = m_in >> 11;
  const int s0m = m_in & (S_LEN - 1);
  const int h0 = n0 >> 6;               // first of 2 heads in this n-span
  const float* __restrict__ X = (z == 0) ? Xq : ((z == 1) ? Xk : Xv);
  X += (size_t)m_in * DM;

  const int t = threadIdx.x;
  const int lane = t & 63;
  const int wid = t >> 6;
  const int wr = wid >> 1, wc = wid & 1;
  const int fr = lane & 15, fg = lane >> 4;

  f32x4 acc[4][4] = {};

  const int lrow = lane >> 3;           // 0..7 within chunk
  const int lblk = lane & 7;            // 16B block within 128B row

  auto stage = [&](int bf, int k0) {
    #pragma unroll
    for (int i = 0; i < 4; ++i) {       // A: 16 chunks of 1KB (8 rows), 4/wave
      int c = wid * 4 + i;
      int r = c * 8 + lrow;
      gload16(X + (size_t)r * DM + k0 + ((lblk ^ (r & 7)) << 2), &BUF[bf][c * 256]);
    }
    #pragma unroll
    for (int i = 0; i < 4; ++i) {       // B: 16 chunks, 4/wave
      int c = wid * 4 + i;
      int r = c * 8 + lrow;
      gload16(W + (size_t)(n0 + r) * DM + k0 + ((lblk ^ (r & 7)) << 2),
              &BUF[bf][4096 + c * 256]);
    }
  };

  stage(0, 0);
  int cb = 0;
  for (int i = 0; i < 16; ++i) {
    __syncthreads();                    // drains prior stage (compiler vmcnt)
    if (i < 15) stage(cb ^ 1, (i + 1) * 32);
    const float* Ac = BUF[cb];
    bf16x8 af[4], bfr[4];
    #pragma unroll
    for (int m2 = 0; m2 < 4; ++m2) {
      int r = wr*64 + m2*16 + fr;
      f32x4 lo = *(const f32x4*)&Ac[r*32 + (((2*fg)     ^ (r & 7)) << 2)];
      f32x4 hi = *(const f32x4*)&Ac[r*32 + (((2*fg + 1) ^ (r & 7)) << 2)];
      union { u16x8 s; bf16x8 v; } f;
      f.s[0]=bfbits(lo[0]); f.s[1]=bfbits(lo[1]); f.s[2]=bfbits(lo[2]); f.s[3]=bfbits(lo[3]);
      f.s[4]=bfbits(hi[0]); f.s[5]=bfbits(hi[1]); f.s[6]=bfbits(hi[2]); f.s[7]=bfbits(hi[3]);
      af[m2] = f.v;
    }
    #pragma unroll
    for (int ni = 0; ni < 4; ++ni) {
      int r = wc*64 + ni*16 + fr;
      f32x4 lo = *(const f32x4*)&Ac[4096 + r*32 + (((2*fg)     ^ (r & 7)) << 2)];
      f32x4 hi = *(const f32x4*)&Ac[4096 + r*32 + (((2*fg + 1) ^ (r & 7)) << 2)];
      union { u16x8 s; bf16x8 v; } f;
      f.s[0]=bfbits(lo[0]); f.s[1]=bfbits(lo[1]); f.s[2]=bfbits(lo[2]); f.s[3]=bfbits(lo[3]);
      f.s[4]=bfbits(hi[0]); f.s[5]=bfbits(hi[1]); f.s[6]=bfbits(hi[2]); f.s[7]=bfbits(hi[3]);
      bfr[ni] = f.v;
    }
    __builtin_amdgcn_s_setprio(1);
    #pragma unroll
    for (int m2 = 0; m2 < 4; ++m2)
      #pragma unroll
      for (int ni = 0; ni < 4; ++ni)
        acc[m2][ni] = __builtin_amdgcn_mfma_f32_16x16x32_bf16(af[m2], bfr[ni], acc[m2][ni], 0, 0, 0);
    __builtin_amdgcn_s_setprio(0);
    cb ^= 1;
  }
  __syncthreads();

  const float QSCALE = 0.125f * 1.44269504089f;
  u16* epi = (u16*)&BUF[0][0];          // 128 x 136 u16 = 34 KB, fits 64 KB pool

  if (z == 2) {
    // stage C^T[e][m] (stride 136); coalesced rows -> Vt64[bh][s/64][d][s%64]
    #pragma unroll
    for (int m2 = 0; m2 < 4; ++m2) {
      #pragma unroll
      for (int ni = 0; ni < 4; ++ni) {
        int e = wc*64 + ni*16 + fr;
        int m = wr*64 + m2*16 + fg*4;
        float bv = bias[n0 + e];
        float v0 = fmaxf(acc[m2][ni][0] + bv, 0.f);
        float v1 = fmaxf(acc[m2][ni][1] + bv, 0.f);
        float v2 = fmaxf(acc[m2][ni][2] + bv, 0.f);
        float v3 = fmaxf(acc[m2][ni][3] + bv, 0.f);
        uint2 w; w.x = pkbf(v0, v1); w.y = pkbf(v2, v3);
        *(uint2*)&epi[e*136 + m] = w;
      }
    }
    __syncthreads();
    const int e2 = t >> 1, mc = (t & 1) * 64;   // e2 0..127, mc 0/64
    const int h = h0 + (e2 >> 6), d = e2 & 63;
    const int sb = (s0m >> 6) + (mc >> 6);
    u16* dst = Vt64 + (((size_t)(b * NH + h) * 32 + sb) * 64 + d) * 64;
    #pragma unroll
    for (int i = 0; i < 8; ++i)
      *(uint4*)(dst + i*8) = *(const uint4*)&epi[e2*136 + mc + i*8];
  } else {
    // stage C[m][e] (stride 136); coalesced rows -> Qw/Kw[bh][s][dh]
    #pragma unroll
    for (int m2 = 0; m2 < 4; ++m2) {
      #pragma unroll
      for (int ni = 0; ni < 4; ++ni) {
        int e = wc*64 + ni*16 + fr;
        float bv = bias[n0 + e];
        #pragma unroll
        for (int r = 0; r < 4; ++r) {
          float v = acc[m2][ni][r] + bv;
          if (z == 0) v *= QSCALE;
          v = fmaxf(v, 0.f);
          epi[(wr*64 + m2*16 + fg*4 + r)*136 + e] = bfbits(v);
        }
      }
    }
    __syncthreads();
    const int mrow = t >> 1, hf = t & 1;
    u16* dst = ((z == 0) ? Qw : Kw) +
               (((size_t)(b * NH + h0 + hf)) * S_LEN + s0m + mrow) * DHD;
    #pragma unroll
    for (int i = 0; i < 8; ++i)
      *(uint4*)(dst + i*8) = *(const uint4*)&epi[mrow*136 + hf*64 + i*8];
  }
}

// longest-first block table: (qb, chunk) for the 34 blocks per bh
static __device__ const uint8_t QBT[34] = {4,5,6,7,8,9,9,10,10,11,11,12,12,13,13,14,14,14,15,15,15,
                                           3,8,13, 2,7,12, 1,6,11, 0,5,10,15};
static __device__ const uint8_t CKT[34] = {0,0,0,0,0,0,1,0,1,0,1,0,1,0,1,0,1,2,0,1,2,
                                           0,1,2, 0,1,2, 0,1,2, 0,1,2,3};

// ---------------------------------------------------------------------------
// Flash attention (R25 form): 4 waves/block, FOUR 64-row K/V LDS buffers,
// 2 steps per barrier, stages one iteration ahead; bulk-bulk step pair fused
// with [PV(s) || QK(s+1)] interleave. Unnormalized p=exp2(s).
// ---------------------------------------------------------------------------
__launch_bounds__(256, 2)
__global__ void attn_kernel(const u16* __restrict__ Qw, const u16* __restrict__ Kw,
                            const u16* __restrict__ Vt64, u16* __restrict__ Opart,
                            float* __restrict__ lbuf, float* __restrict__ out) {
  __shared__ u16 KLDS[4][4096];
  __shared__ u16 VLDS[4][4096];
  const int t = threadIdx.x;
  const int lane = t & 63;
  const int wid = t >> 6;
  const int lam = lane & 31;
  const int hi = lane >> 5;
  const int h8 = hi << 3, h4 = hi << 2;
  const int bid = blockIdx.x;
  const int bh = bid & 15;              // xcd = bid&7
  const int u = bid >> 4;               // 0..33
  const int qb = QBT[u], chunk = CKT[u];
  const int steps_total = (qb + 1) * 2;
  const int sc0 = chunk * 10;
  const int sc1e = sc0 + 10;
  const int sc1 = (sc1e < steps_total) ? sc1e : steps_total;
  const int t32 = qb * 4 + wid;
  const int q0 = qb * 128 + wid * 32;

  const u16* __restrict__ Qh = Qw + (size_t)bh * S_LEN * DHD;
  const u16* __restrict__ Kh = Kw + (size_t)bh * S_LEN * DHD;
  const u16* __restrict__ V64 = Vt64 + (size_t)bh * 32 * 64 * 64;

  bf16x8 qf[4];
  #pragma unroll
  for (int c = 0; c < 4; ++c)
    qf[c] = *(const bf16x8*)(Qh + (size_t)(q0 + lam) * DHD + c*16 + h8);

  const int lrow = lane >> 3;           // 0..7 within chunk
  const int lblk = lane & 7;
  auto stage = [&](int bf, int s) {
    #pragma unroll
    for (int i = 0; i < 2; ++i) {       // K,V: 8 chunks of 1KB each, 2 per wave
      int c = wid * 2 + i;
      int r = c * 8 + lrow;             // 0..63
      int sw = (lblk ^ (r & 7)) << 3;   // XOR-pre-swizzled source block (u16)
      gload16(Kh + (size_t)(s * 64 + r) * 64 + sw, &KLDS[bf][c * 512]);
      gload16(V64 + ((size_t)s * 64 + r) * 64 + sw, &VLDS[bf][c * 512]);
    }
  };

  f32x16 o0 = {}, o1 = {};
  float lsum = 0.f;

  auto softpack = [&](const f32x16& sc, bool msk, bf16x8& pb0v, bf16x8& pb1v) {
    float p[16];
    #pragma unroll
    for (int r = 0; r < 16; ++r) {
      float ev = __builtin_amdgcn_exp2f(sc[r]);
      int kc = (r & 3) + ((r >> 2) << 3) + h4;
      if (msk && kc > lam) ev = 0.f;
      p[r] = ev;
      lsum += ev;
    }
    uint32_t X0 = pkbf(p[0], p[1]),  X1 = pkbf(p[2], p[3]);
    uint32_t X2 = pkbf(p[4], p[5]),  X3 = pkbf(p[6], p[7]);
    uint32_t X4 = pkbf(p[8], p[9]),  X5 = pkbf(p[10], p[11]);
    uint32_t X6 = pkbf(p[12], p[13]), X7 = pkbf(p[14], p[15]);
    asm("v_permlane32_swap_b32 %0, %1" : "+v"(X0), "+v"(X2));
    asm("v_permlane32_swap_b32 %0, %1" : "+v"(X1), "+v"(X3));
    asm("v_permlane32_swap_b32 %0, %1" : "+v"(X4), "+v"(X6));
    asm("v_permlane32_swap_b32 %0, %1" : "+v"(X5), "+v"(X7));
    union U8 { uint32_t u[4]; bf16x8 v; };
    U8 a, bU;
    a.u[0] = X0; a.u[1] = X1; a.u[2] = X2; a.u[3] = X3;
    bU.u[0] = X4; bU.u[1] = X5; bU.u[2] = X6; bU.u[3] = X7;
    pb0v = a.v; pb1v = bU.v;
  };

  auto loadK = [&](int buf, int half, bf16x8* k4) {
    #pragma unroll
    for (int c = 0; c < 4; ++c) {
      int r = half * 32 + lam, e = ((2*c + hi) ^ (r & 7)) * 8;
      k4[c] = *(const bf16x8*)&KLDS[buf][r*64 + e];
    }
  };
  auto loadV = [&](int buf, int off, bf16x8* v0, bf16x8* v1) {
    #pragma unroll
    for (int c2 = 0; c2 < 2; ++c2) {
      int r0 = lam,      e0 = ((off + 2*c2 + hi) ^ (r0 & 7)) * 8;
      int r1 = 32 + lam, e1 = ((off + 2*c2 + hi) ^ (r1 & 7)) * 8;
      v0[c2] = *(const bf16x8*)&VLDS[buf][r0*64 + e0];
      v1[c2] = *(const bf16x8*)&VLDS[buf][r1*64 + e1];
    }
  };

  // R24 single-step path (edge cases)
  auto do_step = [&](int s, int buf) {
    const int d2 = t32 - 2 * s;
    if (d2 < 0) return;
    if (d2 >= 1) {
      bf16x8 kA[4], kB[4];
      loadK(buf, 0, kA);
      loadK(buf, 1, kB);
      f32x16 sA = {}, sB = {};
      __builtin_amdgcn_s_setprio(1);
      #pragma unroll
      for (int c = 0; c < 4; ++c) {
        sA = __builtin_amdgcn_mfma_f32_32x32x16_bf16(kA[c], qf[c], sA, 0, 0, 0);
        sB = __builtin_amdgcn_mfma_f32_32x32x16_bf16(kB[c], qf[c], sB, 0, 0, 0);
      }
      __builtin_amdgcn_s_setprio(0);
      bf16x8 a0, a1, b0v, b1v;
      softpack(sA, false, a0, a1);
      softpack(sB, d2 == 1, b0v, b1v);
      bf16x8 vA0[2], vA1[2], vB0[2], vB1[2];
      loadV(buf, 0, vA0, vA1);
      loadV(buf, 4, vB0, vB1);
      __builtin_amdgcn_s_setprio(1);
      o0 = __builtin_amdgcn_mfma_f32_32x32x16_bf16(vA0[0], a0, o0, 0, 0, 0);
      o1 = __builtin_amdgcn_mfma_f32_32x32x16_bf16(vA1[0], a0, o1, 0, 0, 0);
      o0 = __builtin_amdgcn_mfma_f32_32x32x16_bf16(vA0[1], a1, o0, 0, 0, 0);
      o1 = __builtin_amdgcn_mfma_f32_32x32x16_bf16(vA1[1], a1, o1, 0, 0, 0);
      o0 = __builtin_amdgcn_mfma_f32_32x32x16_bf16(vB0[0], b0v, o0, 0, 0, 0);
      o1 = __builtin_amdgcn_mfma_f32_32x32x16_bf16(vB1[0], b0v, o1, 0, 0, 0);
      o0 = __builtin_amdgcn_mfma_f32_32x32x16_bf16(vB0[1], b1v, o0, 0, 0, 0);
      o1 = __builtin_amdgcn_mfma_f32_32x32x16_bf16(vB1[1], b1v, o1, 0, 0, 0);
      __builtin_amdgcn_s_setprio(0);
    } else {
      bf16x8 kA[4];
      loadK(buf, 0, kA);
      f32x16 sA = {};
      __builtin_amdgcn_s_setprio(1);
      #pragma unroll
      for (int c = 0; c < 4; ++c)
        sA = __builtin_amdgcn_mfma_f32_32x32x16_bf16(kA[c], qf[c], sA, 0, 0, 0);
      __builtin_amdgcn_s_setprio(0);
      bf16x8 a0, a1;
      softpack(sA, true, a0, a1);
      bf16x8 v0[2], v1[2];
      loadV(buf, 0, v0, v1);
      __builtin_amdgcn_s_setprio(1);
      o0 = __builtin_amdgcn_mfma_f32_32x32x16_bf16(v0[0], a0, o0, 0, 0, 0);
      o1 = __builtin_amdgcn_mfma_f32_32x32x16_bf16(v1[0], a0, o1, 0, 0, 0);
      o0 = __builtin_amdgcn_mfma_f32_32x32x16_bf16(v0[1], a1, o0, 0, 0, 0);
      o1 = __builtin_amdgcn_mfma_f32_32x32x16_bf16(v1[1], a1, o1, 0, 0, 0);
      __builtin_amdgcn_s_setprio(0);
    }
  };

  // fused step pair: step s (buf b0i, unmasked) + step s+1 (buf b1i, maskB1)
  auto fused_pair = [&](int b0i, int b1i, bool maskB1) {
    bf16x8 kA0[4], kB0[4];
    loadK(b0i, 0, kA0);
    loadK(b0i, 1, kB0);
    f32x16 sA0 = {}, sB0 = {};
    __builtin_amdgcn_s_setprio(1);
    #pragma unroll
    for (int c = 0; c < 4; ++c) {
      sA0 = __builtin_amdgcn_mfma_f32_32x32x16_bf16(kA0[c], qf[c], sA0, 0, 0, 0);
      sB0 = __builtin_amdgcn_mfma_f32_32x32x16_bf16(kB0[c], qf[c], sB0, 0, 0, 0);
    }
    __builtin_amdgcn_s_setprio(0);
    bf16x8 a00, a01, b00, b01;
    softpack(sA0, false, a00, a01);
    softpack(sB0, false, b00, b01);
    bf16x8 kA1[4], kB1[4];
    loadK(b1i, 0, kA1);
    loadK(b1i, 1, kB1);
    bf16x8 vA0[2], vA1[2], vB0[2], vB1[2];
    loadV(b0i, 0, vA0, vA1);
    loadV(b0i, 4, vB0, vB1);
    f32x16 sA1 = {}, sB1 = {};
    __builtin_amdgcn_s_setprio(1);
    o0  = __builtin_amdgcn_mfma_f32_32x32x16_bf16(vA0[0], a00, o0, 0, 0, 0);
    sA1 = __builtin_amdgcn_mfma_f32_32x32x16_bf16(kA1[0], qf[0], sA1, 0, 0, 0);
    o1  = __builtin_amdgcn_mfma_f32_32x32x16_bf16(vA1[0], a00, o1, 0, 0, 0);
    sB1 = __builtin_amdgcn_mfma_f32_32x32x16_bf16(kB1[0], qf[0], sB1, 0, 0, 0);
    o0  = __builtin_amdgcn_mfma_f32_32x32x16_bf16(vA0[1], a01, o0, 0, 0, 0);
    sA1 = __builtin_amdgcn_mfma_f32_32x32x16_bf16(kA1[1], qf[1], sA1, 0, 0, 0);
    o1  = __builtin_amdgcn_mfma_f32_32x32x16_bf16(vA1[1], a01, o1, 0, 0, 0);
    sB1 = __builtin_amdgcn_mfma_f32_32x32x16_bf16(kB1[1], qf[1], sB1, 0, 0, 0);
    o0  = __builtin_amdgcn_mfma_f32_32x32x16_bf16(vB0[0], b00, o0, 0, 0, 0);
    sA1 = __builtin_amdgcn_mfma_f32_32x32x16_bf16(kA1[2], qf[2], sA1, 0, 0, 0);
    o1  = __builtin_amdgcn_mfma_f32_32x32x16_bf16(vB1[0], b00, o1, 0, 0, 0);
    sB1 = __builtin_amdgcn_mfma_f32_32x32x16_bf16(kB1[2], qf[2], sB1, 0, 0, 0);
    o0  = __builtin_amdgcn_mfma_f32_32x32x16_bf16(vB0[1], b01, o0, 0, 0, 0);
    sA1 = __builtin_amdgcn_mfma_f32_32x32x16_bf16(kA1[3], qf[3], sA1, 0, 0, 0);
    o1  = __builtin_amdgcn_mfma_f32_32x32x16_bf16(vB1[1], b01, o1, 0, 0, 0);
    sB1 = __builtin_amdgcn_mfma_f32_32x32x16_bf16(kB1[3], qf[3], sB1, 0, 0, 0);
    __builtin_amdgcn_s_setprio(0);
    bf16x8 a10, a11, b10, b11;
    softpack(sA1, false, a10, a11);
    softpack(sB1, maskB1, b10, b11);
    bf16x8 wA0[2], wA1[2], wB0[2], wB1[2];
    loadV(b1i, 0, wA0, wA1);
    loadV(b1i, 4, wB0, wB1);
    __builtin_amdgcn_s_setprio(1);
    o0 = __builtin_amdgcn_mfma_f32_32x32x16_bf16(wA0[0], a10, o0, 0, 0, 0);
    o1 = __builtin_amdgcn_mfma_f32_32x32x16_bf16(wA1[0], a10, o1, 0, 0, 0);
    o0 = __builtin_amdgcn_mfma_f32_32x32x16_bf16(wA0[1], a11, o0, 0, 0, 0);
    o1 = __builtin_amdgcn_mfma_f32_32x32x16_bf16(wA1[1], a11, o1, 0, 0, 0);
    o0 = __builtin_amdgcn_mfma_f32_32x32x16_bf16(wB0[0], b10, o0, 0, 0, 0);
    o1 = __builtin_amdgcn_mfma_f32_32x32x16_bf16(wB1[0], b10, o1, 0, 0, 0);
    o0 = __builtin_amdgcn_mfma_f32_32x32x16_bf16(wB0[1], b11, o0, 0, 0, 0);
    o1 = __builtin_amdgcn_mfma_f32_32x32x16_bf16(wB1[1], b11, o1, 0, 0, 0);
    __builtin_amdgcn_s_setprio(0);
  };

  // 2 steps per barrier; stages issued one full iteration ahead.
  stage(0, sc0);
  stage(1, sc0 + 1);
  int ib = 0;
  for (int s = sc0; s < sc1; s += 2) {
    __syncthreads();                    // drains stages issued LAST iteration
    if (s + 2 < sc1) {
      stage((ib + 2) & 3, s + 2);
      stage((ib + 3) & 3, s + 3);
    }
    const int d2s = t32 - 2 * s;        // wave-uniform
    if (d2s >= 3) {
      fused_pair(ib, (ib + 1) & 3, d2s == 3);
    } else {
      do_step(s, ib);
      do_step(s + 1, (ib + 1) & 3);
    }
    ib = (ib + 2) & 3;
  }

  float l = lsum + __shfl_xor(lsum, 32);

  if (qb <= 4) {
    const int b = bh >> 3, hh = bh & 7;
    const float inv = 1.0f / l;
    float* orow = out + (((size_t)(hh * NB + b)) * S_LEN + (q0 + lam)) * DHD;
    #pragma unroll
    for (int r = 0; r < 16; ++r) {
      int d = (r & 3) + ((r >> 2) << 3) + h4;
      orow[d] = o0[r] * inv;
      orow[d + 32] = o1[r] * inv;
    }
  } else {
    const int slot = slot_of(bh, t32, chunk);
    uint32_t w[16] __attribute__((aligned(16)));
    #pragma unroll
    for (int m = 0; m < 8; ++m) {
      w[m]     = pkbf(o0[2*m], o0[2*m+1]);
      w[8 + m] = pkbf(o1[2*m], o1[2*m+1]);
    }
    u16* op = Opart + (size_t)slot * 2048 + (size_t)lane * 32;
    #pragma unroll
    for (int i = 0; i < 4; ++i)
      *(uint4*)(op + i*8) = *(const uint4*)&w[i*4];
    if (lane < 32) lbuf[slot * 32 + lane] = l;
  }
}

// ---------------------------------------------------------------------------
// Combine split-K partials for tiles with qb>=5 (t32 20..63): plain sums.
// ---------------------------------------------------------------------------
__launch_bounds__(256)
__global__ void reduce_kernel(const u16* __restrict__ Opart,
                              const float* __restrict__ lbuf,
                              float* __restrict__ out) {
  const int t = threadIdx.x;
  const int unit = blockIdx.x * 4 + (t >> 6);   // 0..703
  const int bh = unit & 15;
  const int ti = 20 + (unit >> 4);              // t32 20..63
  const int qb = ti >> 2;
  const int nc = (2 * (qb + 1) + 9) / 10;       // 2..4
  const int lane = t & 63;
  const int lam = lane & 31;
  const int h4 = (lane >> 5) << 2;
  const int slot0 = slot_of(bh, ti, 0);

  float O[32];
  #pragma unroll
  for (int i = 0; i < 32; ++i) O[i] = 0.f;
  float L = 0.f;

  for (int c = 0; c < nc; ++c) {
    const u16* op = Opart + (size_t)(slot0 + c) * 2048 + (size_t)lane * 32;
    L += lbuf[(slot0 + c) * 32 + lam];
    #pragma unroll
    for (int i = 0; i < 4; ++i) {
      uint4 v = *(const uint4*)(op + i*8);
      uint32_t a[4] = {v.x, v.y, v.z, v.w};
      #pragma unroll
      for (int jj = 0; jj < 4; ++jj) {
        O[i*8 + 2*jj]     += bits2f((u16)(a[jj] & 0xFFFFu));
        O[i*8 + 2*jj + 1] += bits2f((u16)(a[jj] >> 16));
      }
    }
  }

  const int b = bh >> 3, hh = bh & 7;
  const float inv = 1.0f / L;
  float* orow = out + (((size_t)(hh * NB + b)) * S_LEN + (ti*32 + lam)) * DHD;
  #pragma unroll
  for (int r = 0; r < 16; ++r) {
    int d = (r & 3) + ((r >> 2) << 3) + h4;
    orow[d] = O[r] * inv;
    orow[d + 32] = O[16 + r] * inv;
  }
}

extern "C" void kernel_launch(void* const* d_in, const int* in_sizes, int n_in,
                              void* d_out, int out_size, void* d_ws, size_t ws_size,
                              hipStream_t stream) {
  const float* q = (const float*)d_in[0];
  const float* k = (const float*)d_in[1];
  const float* v = (const float*)d_in[2];
  const float* W = (const float*)d_in[3];
  const float* b = (const float*)d_in[4];

  const size_t elems = (size_t)NB * NH * S_LEN * DHD;  // 2,097,152
  u16* Qw = (u16*)d_ws;
  u16* Kw = Qw + elems;
  u16* Vt64 = Kw + elems;
  u16* Opart = Vt64 + elems;                           // 1856 slots * 4 KiB = 7.25 MiB
  float* lbuf = (float*)(Opart + (size_t)1856 * 2048); // 232 KiB

  proj_kernel<<<dim3(384), dim3(256), 0, stream>>>(q, k, v, W, b, Qw, Kw, Vt64);

  attn_kernel<<<dim3(544), dim3(256), 0, stream>>>(Qw, Kw, Vt64, Opart, lbuf, (float*)d_out);

  reduce_kernel<<<dim3(176), dim3(256), 0, stream>>>(Opart, lbuf, (float*)d_out);
}